// Round 1
// baseline (209.013 us; speedup 1.0000x reference)
//
#include <hip/hip_runtime.h>
#include <hip/hip_bf16.h>
#include <stdint.h>

#define B 4
#define N 256
#define D 128
#define H 256
#define MAXE 8192          // expected ~3200 edges/batch (90+ sigma headroom)
#define TILE_E 16
#define NT (MAXE / TILE_E) // 512 edge tiles per batch

// ---------------------------------------------------------------- K1: adjacency bitmasks + edge list
__global__ __launch_bounds__(64) void k_adj_edges(
    const float* __restrict__ A, uint64_t* __restrict__ adjMask,
    unsigned* __restrict__ edgeCnt, unsigned* __restrict__ edges) {
  int blk = blockIdx.x;            // B*N blocks
  int b = blk >> 8, j = blk & 255;
  int lane = threadIdx.x;          // 64 = one wave
  const float* Arow = A + ((size_t)(b * N + j)) * N;
  for (int c = 0; c < 4; ++c) {
    int k = c * 64 + lane;
    float a = Arow[k];
    uint64_t m = __ballot(a != 0.0f);
    if (lane == 0) adjMask[(b * N + j) * 4 + c] = m;
    bool ed = (a != 0.0f) && (k > j);          // each undirected edge once (j<k)
    uint64_t em = __ballot(ed);
    int cnt = __popcll(em);
    int base = 0;
    if (lane == 0 && cnt) base = (int)atomicAdd(&edgeCnt[b], (unsigned)cnt);
    base = __shfl(base, 0);
    if (ed) {
      int rank = __popcll(em & ((1ull << lane) - 1ull));
      unsigned slot = (unsigned)(base + rank);
      if (slot < MAXE) edges[b * MAXE + slot] = ((unsigned)j << 8) | (unsigned)k;
    }
  }
}

// ---------------------------------------------------------------- K2: X_std = ((1+eps)I + A) @ X  (sparse via bitmask)
__global__ __launch_bounds__(128) void k_xstd(
    const float* __restrict__ X, const float* __restrict__ eps,
    const uint64_t* __restrict__ adjMask, float* __restrict__ Xn) {
  int blk = blockIdx.x;            // B*N blocks
  int b = blk >> 8, i = blk & 255;
  int d = threadIdx.x;             // 128
  float acc = (1.0f + eps[0]) * X[((size_t)(b * N + i)) * D + d];
  const uint64_t* m = &adjMask[(b * N + i) * 4];
  for (int c = 0; c < 4; ++c) {
    uint64_t mm = m[c];
    while (mm) {
      int j = c * 64 + __builtin_ctzll(mm);
      mm &= mm - 1;
      acc += X[((size_t)(b * N + j)) * D + d];
    }
  }
  Xn[((size_t)(b * N + i)) * D + d] = acc;
}

// ---------------------------------------------------------------- K3: per-edge MLP2 + triangle scatter (fused)
__global__ __launch_bounds__(256) void k_mlp2(
    const float* __restrict__ X, const unsigned* __restrict__ edges,
    const unsigned* __restrict__ edgeCnt, const uint64_t* __restrict__ adjMask,
    const float* __restrict__ W3, const float* __restrict__ b3,
    const float* __restrict__ W4, const float* __restrict__ b4,
    float* __restrict__ Xn) {
  __shared__ unsigned eLds[TILE_E];
  __shared__ float psum[TILE_E * D];   // 8 KB
  __shared__ float hid[TILE_E * H];    // 16 KB
  int blk = blockIdx.x;                // B*NT blocks
  int b = blk / NT;
  int t0 = (blk % NT) * TILE_E;
  unsigned cnt = min(edgeCnt[b], (unsigned)MAXE);
  if ((unsigned)t0 >= cnt) return;     // uniform exit, before any barrier
  int nE = min(TILE_E, (int)(cnt - (unsigned)t0));
  int tid = threadIdx.x;
  if (tid < TILE_E) eLds[tid] = (tid < nE) ? edges[b * MAXE + t0 + tid] : 0u;
  __syncthreads();
  // stage pair sums P[j]+P[k]
  for (int idx = tid; idx < TILE_E * D; idx += 256) {
    int e = idx >> 7, c = idx & 127;
    unsigned ev = eLds[e];
    int j = (int)((ev >> 8) & 255u), k = (int)(ev & 255u);
    psum[idx] = X[((size_t)(b * N + j)) * D + c] + X[((size_t)(b * N + k)) * D + c];
  }
  __syncthreads();
  // layer 1: hidden[e][h], h = tid (K=128)
  {
    float acc[TILE_E];
#pragma unroll
    for (int e = 0; e < TILE_E; ++e) acc[e] = 0.0f;
    for (int c = 0; c < D; c += 4) {
      float w0 = W3[(c + 0) * H + tid];
      float w1 = W3[(c + 1) * H + tid];
      float w2 = W3[(c + 2) * H + tid];
      float w3v = W3[(c + 3) * H + tid];
#pragma unroll
      for (int e = 0; e < TILE_E; ++e) {
        const float4 p = *(const float4*)&psum[e * D + c];
        acc[e] = fmaf(p.x, w0, fmaf(p.y, w1, fmaf(p.z, w2, fmaf(p.w, w3v, acc[e]))));
      }
    }
    float bb = b3[tid];
#pragma unroll
    for (int e = 0; e < TILE_E; ++e) hid[e * H + tid] = fmaxf(acc[e] + bb, 0.0f);
  }
  __syncthreads();
  // layer 2: out[e][d], thread owns (g = tid>>7 -> edges g*8..g*8+7, d = tid&127), K=256
  {
    int d = tid & 127;
    int g = tid >> 7;
    float acc2[8];
#pragma unroll
    for (int e = 0; e < 8; ++e) acc2[e] = 0.0f;
    for (int h = 0; h < H; h += 4) {
      float w0 = W4[(h + 0) * D + d];
      float w1 = W4[(h + 1) * D + d];
      float w2 = W4[(h + 2) * D + d];
      float w3v = W4[(h + 3) * D + d];
#pragma unroll
      for (int e = 0; e < 8; ++e) {
        const float4 hv = *(const float4*)&hid[(g * 8 + e) * H + h];
        acc2[e] = fmaf(hv.x, w0, fmaf(hv.y, w1, fmaf(hv.z, w2, fmaf(hv.w, w3v, acc2[e]))));
      }
    }
    float bb = b4[d];
#pragma unroll
    for (int e = 0; e < 8; ++e) {
      int ee = g * 8 + e;
      if (ee >= nE) break;
      float v = fmaxf(acc2[e] + bb, 0.0f);
      unsigned ev = eLds[ee];
      int j = (int)((ev >> 8) & 255u), k = (int)(ev & 255u);
      const uint64_t* mj = &adjMask[(b * N + j) * 4];
      const uint64_t* mk = &adjMask[(b * N + k) * 4];
#pragma unroll
      for (int w = 0; w < 4; ++w) {
        uint64_t cm = mj[w] & mk[w];   // common neighbors of (j,k)
        while (cm) {
          int i = w * 64 + __builtin_ctzll(cm);
          cm &= cm - 1;
          atomicAdd(&Xn[((size_t)(b * N + i)) * D + d], v);
        }
      }
    }
  }
}

// ---------------------------------------------------------------- K4: H1 = relu(Xn@W1+b1) + BN1 stats
__global__ __launch_bounds__(256) void k_mlp1a(
    const float* __restrict__ Xn, const float* __restrict__ W1,
    const float* __restrict__ b1, float* __restrict__ H1,
    float* __restrict__ bn1s, float* __restrict__ bn1q) {
  __shared__ float xr[D];
  int blk = blockIdx.x;            // B*N
  int b = blk >> 8, n = blk & 255;
  int tid = threadIdx.x;           // 256
  if (tid < D) xr[tid] = Xn[((size_t)(b * N + n)) * D + tid];
  __syncthreads();
  float acc = b1[tid];
  for (int c = 0; c < D; c += 4) {
    const float4 x = *(const float4*)&xr[c];
    acc = fmaf(x.x, W1[(c + 0) * H + tid], acc);
    acc = fmaf(x.y, W1[(c + 1) * H + tid], acc);
    acc = fmaf(x.z, W1[(c + 2) * H + tid], acc);
    acc = fmaf(x.w, W1[(c + 3) * H + tid], acc);
  }
  float v = fmaxf(acc, 0.0f);
  H1[((size_t)(b * N + n)) * H + tid] = v;
  float s = v, q = v * v;
  for (int off = 32; off; off >>= 1) {
    s += __shfl_down(s, off);
    q += __shfl_down(q, off);
  }
  if ((tid & 63) == 0) {
    atomicAdd(&bn1s[n], s);
    atomicAdd(&bn1q[n], q);
  }
}

// ---------------------------------------------------------------- K5: BN1-apply (scalar affine per row) + H2 = relu(.@W2+b2) + BN2 stats
__global__ __launch_bounds__(256) void k_mlp1b(
    const float* __restrict__ H1, const float* __restrict__ W2,
    const float* __restrict__ b2, const float* __restrict__ g1,
    const float* __restrict__ be1, const float* __restrict__ bn1s,
    const float* __restrict__ bn1q, float* __restrict__ H2,
    float* __restrict__ bn2s, float* __restrict__ bn2q) {
  __shared__ float zr[H];
  int blk = blockIdx.x;            // B*N
  int b = blk >> 8, n = blk & 255;
  int tid = threadIdx.x;           // 256
  float mean = bn1s[n] * (1.0f / 1024.0f);
  float var = bn1q[n] * (1.0f / 1024.0f) - mean * mean;  // biased, matches jnp.var
  float inv = rsqrtf(var + 1e-5f);
  float a = g1[n] * inv;
  float c0 = be1[n] - a * mean;
  zr[tid] = a * H1[((size_t)(b * N + n)) * H + tid] + c0;
  __syncthreads();
  float acc = b2[tid];
  for (int c = 0; c < H; c += 4) {
    const float4 z = *(const float4*)&zr[c];
    acc = fmaf(z.x, W2[(c + 0) * H + tid], acc);
    acc = fmaf(z.y, W2[(c + 1) * H + tid], acc);
    acc = fmaf(z.z, W2[(c + 2) * H + tid], acc);
    acc = fmaf(z.w, W2[(c + 3) * H + tid], acc);
  }
  float v = fmaxf(acc, 0.0f);
  H2[((size_t)(b * N + n)) * H + tid] = v;
  float s = v, q = v * v;
  for (int off = 32; off; off >>= 1) {
    s += __shfl_down(s, off);
    q += __shfl_down(q, off);
  }
  if ((tid & 63) == 0) {
    atomicAdd(&bn2s[n], s);
    atomicAdd(&bn2q[n], q);
  }
}

// ---------------------------------------------------------------- K6: out = BN2(H2)
__global__ __launch_bounds__(256) void k_bn2out(
    const float* __restrict__ H2, const float* __restrict__ g2,
    const float* __restrict__ be2, const float* __restrict__ bn2s,
    const float* __restrict__ bn2q, float* __restrict__ out) {
  int idx = blockIdx.x * 256 + threadIdx.x;  // B*N*H
  int n = (idx >> 8) & 255;
  float mean = bn2s[n] * (1.0f / 1024.0f);
  float var = bn2q[n] * (1.0f / 1024.0f) - mean * mean;
  float inv = rsqrtf(var + 1e-5f);
  out[idx] = g2[n] * (H2[idx] - mean) * inv + be2[n];
}

// ----------------------------------------------------------------
extern "C" void kernel_launch(void* const* d_in, const int* in_sizes, int n_in,
                              void* d_out, int out_size, void* d_ws, size_t ws_size,
                              hipStream_t stream) {
  const float* A   = (const float*)d_in[0];
  const float* X   = (const float*)d_in[1];
  const float* eps = (const float*)d_in[2];
  const float* W1  = (const float*)d_in[3];
  const float* b1  = (const float*)d_in[4];
  const float* g1  = (const float*)d_in[5];
  const float* be1 = (const float*)d_in[6];
  const float* W2  = (const float*)d_in[7];
  const float* b2  = (const float*)d_in[8];
  const float* g2  = (const float*)d_in[9];
  const float* be2 = (const float*)d_in[10];
  const float* W3  = (const float*)d_in[11];
  const float* b3  = (const float*)d_in[12];
  const float* W4  = (const float*)d_in[13];
  const float* b4  = (const float*)d_in[14];
  float* out = (float*)d_out;

  char* ws = (char*)d_ws;
  uint64_t* adjMask = (uint64_t*)ws; ws += (size_t)B * N * 4 * 8;   // 32 KB
  unsigned* edgeCnt = (unsigned*)ws; ws += 256;
  unsigned* edges   = (unsigned*)ws; ws += (size_t)B * MAXE * 4;    // 128 KB
  float* Xn   = (float*)ws;          ws += (size_t)B * N * D * 4;   // 512 KB
  float* H1   = (float*)ws;          ws += (size_t)B * N * H * 4;   // 1 MB
  float* H2   = (float*)ws;          ws += (size_t)B * N * H * 4;   // 1 MB
  float* bn1s = (float*)ws;          ws += N * 4;
  float* bn1q = (float*)ws;          ws += N * 4;
  float* bn2s = (float*)ws;          ws += N * 4;
  float* bn2q = (float*)ws;          ws += N * 4;                   // bn* contiguous: 4 KB

  hipMemsetAsync(edgeCnt, 0, 256, stream);
  hipMemsetAsync(bn1s, 0, 4 * N * sizeof(float), stream);

  k_adj_edges<<<B * N, 64, 0, stream>>>(A, adjMask, edgeCnt, edges);
  k_xstd<<<B * N, D, 0, stream>>>(X, eps, adjMask, Xn);
  k_mlp2<<<B * NT, 256, 0, stream>>>(X, edges, edgeCnt, adjMask, W3, b3, W4, b4, Xn);
  k_mlp1a<<<B * N, H, 0, stream>>>(Xn, W1, b1, H1, bn1s, bn1q);
  k_mlp1b<<<B * N, H, 0, stream>>>(H1, W2, b2, g1, be1, bn1s, bn1q, H2, bn2s, bn2q);
  k_bn2out<<<(B * N * H) / 256, 256, 0, stream>>>(H2, g2, be2, bn2s, bn2q, out);
}

// Round 6
// 172.588 us; speedup vs baseline: 1.2110x; 1.2110x over previous
//
#include <hip/hip_runtime.h>
#include <hip/hip_bf16.h>
#include <stdint.h>

#define B 4
#define N 256
#define D 128
#define H 256
#define MAXE 8192
#define TILE_E 16
#define NT (MAXE / TILE_E)

typedef __attribute__((ext_vector_type(8))) short bf16x8;
typedef __attribute__((ext_vector_type(4))) float f32x4;

__device__ __forceinline__ ushort f2b(float f) {
  __hip_bfloat16 h = __float2bfloat16(f);
  return *reinterpret_cast<ushort*>(&h);
}

// XOR swizzle: toggle byte-offset bits 4-6 by row (stays within >=128B rows, keeps 16B align)
#define SWZ(off, row) ((off) ^ (((row) & 7) << 4))

// ---------------------------------------------------------------- K0: weights -> bf16 transposed
__global__ __launch_bounds__(256) void k_prep(
    const float* __restrict__ W3, const float* __restrict__ W4,
    ushort* __restrict__ W3T, ushort* __restrict__ W4T) {
  int idx = blockIdx.x * 256 + threadIdx.x;       // 65536
  if (idx < D * H) {                              // W3T[h][c] = W3[c][h]
    int h = idx >> 7, c = idx & 127;
    W3T[h * D + c] = f2b(W3[c * H + h]);
  } else {                                        // W4T[d][h] = W4[h][d]
    int i2 = idx - D * H;
    int d = i2 >> 8, h = i2 & 255;
    W4T[d * H + h] = f2b(W4[h * D + d]);
  }
}

// ---------------------------------------------------------------- K1: bitmasks + neighbor lists + edge list
__global__ __launch_bounds__(64) void k_adj_edges(
    const float* __restrict__ A, uint64_t* __restrict__ adjMask,
    unsigned* __restrict__ deg, uint8_t* __restrict__ nbr,
    unsigned* __restrict__ edgeCnt, unsigned* __restrict__ edges) {
  int blk = blockIdx.x;
  int b = blk >> 8, j = blk & 255;
  int lane = threadIdx.x;
  int row = b * N + j;
  const float* Arow = A + (size_t)row * N;

  uint64_t m0 = __ballot(Arow[lane] != 0.0f);
  uint64_t m1 = __ballot(Arow[64 + lane] != 0.0f);
  uint64_t m2 = __ballot(Arow[128 + lane] != 0.0f);
  uint64_t m3 = __ballot(Arow[192 + lane] != 0.0f);
  if (lane == 0) {
    adjMask[row * 4 + 0] = m0; adjMask[row * 4 + 1] = m1;
    adjMask[row * 4 + 2] = m2; adjMask[row * 4 + 3] = m3;
  }
  int c0 = __popcll(m0), c1 = __popcll(m1), c2 = __popcll(m2), c3 = __popcll(m3);
  int total = c0 + c1 + c2 + c3;
  if (lane == 0) deg[row] = (unsigned)min(total, 64);

  uint64_t lt = (1ull << lane) - 1ull;
  // neighbor list (deterministic slots: chunk-prefix + rank)
  uint8_t* nr = nbr + (size_t)row * 64;
  if ((m0 >> lane) & 1) { int s = __popcll(m0 & lt);                 if (s < 64) nr[s] = (uint8_t)lane; }
  if ((m1 >> lane) & 1) { int s = c0 + __popcll(m1 & lt);            if (s < 64) nr[s] = (uint8_t)(64 + lane); }
  if ((m2 >> lane) & 1) { int s = c0 + c1 + __popcll(m2 & lt);       if (s < 64) nr[s] = (uint8_t)(128 + lane); }
  if ((m3 >> lane) & 1) { int s = c0 + c1 + c2 + __popcll(m3 & lt);  if (s < 64) nr[s] = (uint8_t)(192 + lane); }

  // edges with k > j; ONE atomic per block
  auto gtm = [&](int c) -> uint64_t {
    int lo = j - c * 64;
    if (lo < 0) return ~0ull;
    if (lo >= 63) return 0ull;
    return ~((2ull << lo) - 1ull);
  };
  uint64_t e0 = m0 & gtm(0), e1 = m1 & gtm(1), e2 = m2 & gtm(2), e3 = m3 & gtm(3);
  int t0c = __popcll(e0), t1c = __popcll(e1), t2c = __popcll(e2);
  int et = t0c + t1c + t2c + __popcll(e3);
  unsigned base = 0;
  if (lane == 0 && et) base = atomicAdd(&edgeCnt[b], (unsigned)et);
  base = (unsigned)__shfl((int)base, 0);
  unsigned* eb = edges + (size_t)b * MAXE;
  unsigned tag = ((unsigned)j << 8);
  if ((e0 >> lane) & 1) { unsigned s = base + __popcll(e0 & lt);                   if (s < MAXE) eb[s] = tag | (unsigned)lane; }
  if ((e1 >> lane) & 1) { unsigned s = base + t0c + __popcll(e1 & lt);             if (s < MAXE) eb[s] = tag | (unsigned)(64 + lane); }
  if ((e2 >> lane) & 1) { unsigned s = base + t0c + t1c + __popcll(e2 & lt);       if (s < MAXE) eb[s] = tag | (unsigned)(128 + lane); }
  if ((e3 >> lane) & 1) { unsigned s = base + t0c + t1c + t2c + __popcll(e3 & lt); if (s < MAXE) eb[s] = tag | (unsigned)(192 + lane); }
}

// ---------------------------------------------------------------- K2: X_std via neighbor list (4-way ILP)
__global__ __launch_bounds__(128) void k_xstd(
    const float* __restrict__ X, const float* __restrict__ eps,
    const unsigned* __restrict__ deg, const uint8_t* __restrict__ nbr,
    float* __restrict__ Xn) {
  int blk = blockIdx.x;
  int b = blk >> 8, i = blk & 255;
  int d = threadIdx.x;
  int row = b * N + i;
  const uint8_t* nr = nbr + (size_t)row * 64;
  int dg = (int)deg[row];
  const float* Xb = X + ((size_t)b * N) * D;
  float a0 = (1.0f + eps[0]) * Xb[(size_t)i * D + d];
  float a1 = 0.f, a2 = 0.f, a3 = 0.f;
  int s = 0;
  for (; s + 4 <= dg; s += 4) {
    int n0 = nr[s], n1 = nr[s + 1], n2 = nr[s + 2], n3 = nr[s + 3];
    a0 += Xb[(size_t)n0 * D + d];
    a1 += Xb[(size_t)n1 * D + d];
    a2 += Xb[(size_t)n2 * D + d];
    a3 += Xb[(size_t)n3 * D + d];
  }
  for (; s < dg; ++s) a0 += Xb[(size_t)nr[s] * D + d];
  Xn[(size_t)row * D + d] = (a0 + a1) + (a2 + a3);
}

// ---------------------------------------------------------------- K3: per-edge MLP2 (MFMA bf16) + triangle scatter
// LDS: [0,4K) psum bf16[16][128] (swz) -> reused as [0,8K) Fp f32[16][128]
//      [8K,16K) hid bf16[16][256] (swz)
#define HID_OFF 8192
__global__ __launch_bounds__(256) void k_mlp2(
    const float* __restrict__ X, const unsigned* __restrict__ edges,
    const unsigned* __restrict__ edgeCnt, const uint64_t* __restrict__ adjMask,
    const ushort* __restrict__ W3T, const float* __restrict__ b3,
    const ushort* __restrict__ W4T, const float* __restrict__ b4,
    float* __restrict__ Xn) {
  __shared__ __align__(16) char smem[16384];
  __shared__ unsigned eLds[TILE_E];
  int blk = blockIdx.x;
  int b = blk / NT;
  int t0 = (blk % NT) * TILE_E;
  unsigned cnt = min(edgeCnt[b], (unsigned)MAXE);
  if ((unsigned)t0 >= cnt) return;          // uniform exit before any barrier
  int nE = min(TILE_E, (int)(cnt - (unsigned)t0));
  int tid = threadIdx.x;
  int w = tid >> 6, l = tid & 63, r = l & 15, g = l >> 4;
  const float* Xb = X + ((size_t)b * N) * D;

  if (tid < TILE_E) eLds[tid] = (tid < nE) ? edges[(size_t)b * MAXE + t0 + tid] : 0u;
  __syncthreads();

  // stage pair sums -> bf16 psum (swizzled)
  for (int idx = tid; idx < TILE_E * 64; idx += 256) {
    int e = idx >> 6, cp = idx & 63;
    unsigned ev = eLds[e];
    int j = (int)((ev >> 8) & 255u), k = (int)(ev & 255u);
    float2 xa = *(const float2*)(Xb + (size_t)j * D + cp * 2);
    float2 xb = *(const float2*)(Xb + (size_t)k * D + cp * 2);
    uint pk = (uint)f2b(xa.x + xb.x) | ((uint)f2b(xa.y + xb.y) << 16);
    *(uint*)(smem + e * 256 + SWZ(cp * 4, e)) = pk;
  }
  __syncthreads();

  // ---- layer 1: hid[16][256] = relu(psum @ W3 + b3), wave w owns h in [w*64, w*64+64)
  {
    bf16x8 afr[4];
#pragma unroll
    for (int ks = 0; ks < 4; ++ks)
      afr[ks] = *(const bf16x8*)(smem + r * 256 + SWZ(ks * 64 + g * 16, r));
    f32x4 acc[4];
#pragma unroll
    for (int t = 0; t < 4; ++t) acc[t] = (f32x4){0.f, 0.f, 0.f, 0.f};
#pragma unroll
    for (int t = 0; t < 4; ++t) {
      int h0 = w * 64 + t * 16 + r;
#pragma unroll
      for (int ks = 0; ks < 4; ++ks) {
        bf16x8 bfr = *(const bf16x8*)(W3T + (size_t)h0 * D + ks * 32 + g * 8);
        acc[t] = __builtin_amdgcn_mfma_f32_16x16x32_bf16(afr[ks], bfr, acc[t], 0, 0, 0);
      }
    }
#pragma unroll
    for (int t = 0; t < 4; ++t) {
      int h0 = w * 64 + t * 16 + r;
      float bb = b3[h0];
#pragma unroll
      for (int j = 0; j < 4; ++j) {
        int e = g * 4 + j;
        float v = fmaxf(acc[t][j] + bb, 0.0f);
        *(ushort*)(smem + HID_OFF + e * 512 + SWZ(h0 * 2, e)) = f2b(v);
      }
    }
  }
  __syncthreads();

  // ---- layer 2: Fp[16][128] = relu(hid @ W4 + b4), wave w owns d in [w*32, w*32+32)
  {
    f32x4 acc2[2];
    acc2[0] = (f32x4){0.f, 0.f, 0.f, 0.f};
    acc2[1] = (f32x4){0.f, 0.f, 0.f, 0.f};
#pragma unroll
    for (int ks = 0; ks < 8; ++ks) {
      bf16x8 af = *(const bf16x8*)(smem + HID_OFF + r * 512 + SWZ(ks * 64 + g * 16, r));
#pragma unroll
      for (int t = 0; t < 2; ++t) {
        int d0 = (w * 2 + t) * 16 + r;
        bf16x8 bfr = *(const bf16x8*)(W4T + (size_t)d0 * H + ks * 32 + g * 8);
        acc2[t] = __builtin_amdgcn_mfma_f32_16x16x32_bf16(af, bfr, acc2[t], 0, 0, 0);
      }
    }
    // psum region is dead (last read before previous barrier) -> write Fp f32 over [0,8K)
#pragma unroll
    for (int t = 0; t < 2; ++t) {
      int d0 = (w * 2 + t) * 16 + r;
      float bb = b4[d0];
#pragma unroll
      for (int j = 0; j < 4; ++j) {
        int e = g * 4 + j;
        *(float*)(smem + e * 512 + d0 * 4) = fmaxf(acc2[t][j] + bb, 0.0f);
      }
    }
  }
  __syncthreads();

  // ---- triangle scatter: thread (g2, d) walks edges g2*8..g2*8+7
  {
    int d = tid & 127, g2 = tid >> 7;
    for (int e = 0; e < 8; ++e) {
      int ee = g2 * 8 + e;
      if (ee >= nE) break;
      float v = *(const float*)(smem + ee * 512 + d * 4);
      unsigned ev = eLds[ee];
      int j = (int)((ev >> 8) & 255u), k = (int)(ev & 255u);
      const uint64_t* mj = &adjMask[(b * N + j) * 4];
      const uint64_t* mk = &adjMask[(b * N + k) * 4];
#pragma unroll
      for (int c = 0; c < 4; ++c) {
        uint64_t cm = mj[c] & mk[c];
        while (cm) {
          int i = c * 64 + __builtin_ctzll(cm);
          cm &= cm - 1;
          atomicAdd(&Xn[((size_t)(b * N + i)) * D + d], v);
        }
      }
    }
  }
}

// ---------------------------------------------------------------- K4: H1 = relu(Xn@W1+b1) + BN1 stats
__global__ __launch_bounds__(256) void k_mlp1a(
    const float* __restrict__ Xn, const float* __restrict__ W1,
    const float* __restrict__ b1, float* __restrict__ H1,
    float* __restrict__ bn1s, float* __restrict__ bn1q) {
  __shared__ float xr[D];
  int blk = blockIdx.x;
  int b = blk >> 8, n = blk & 255;
  int tid = threadIdx.x;
  if (tid < D) xr[tid] = Xn[((size_t)(b * N + n)) * D + tid];
  __syncthreads();
  float acc = b1[tid];
  for (int c = 0; c < D; c += 4) {
    const float4 x = *(const float4*)&xr[c];
    acc = fmaf(x.x, W1[(c + 0) * H + tid], acc);
    acc = fmaf(x.y, W1[(c + 1) * H + tid], acc);
    acc = fmaf(x.z, W1[(c + 2) * H + tid], acc);
    acc = fmaf(x.w, W1[(c + 3) * H + tid], acc);
  }
  float v = fmaxf(acc, 0.0f);
  H1[((size_t)(b * N + n)) * H + tid] = v;
  float s = v, q = v * v;
  for (int off = 32; off; off >>= 1) {
    s += __shfl_down(s, off);
    q += __shfl_down(q, off);
  }
  if ((tid & 63) == 0) {
    atomicAdd(&bn1s[n], s);
    atomicAdd(&bn1q[n], q);
  }
}

// ---------------------------------------------------------------- K5: BN1-apply + H2 = relu(.@W2+b2) + BN2 stats
__global__ __launch_bounds__(256) void k_mlp1b(
    const float* __restrict__ H1, const float* __restrict__ W2,
    const float* __restrict__ b2, const float* __restrict__ g1,
    const float* __restrict__ be1, const float* __restrict__ bn1s,
    const float* __restrict__ bn1q, float* __restrict__ H2,
    float* __restrict__ bn2s, float* __restrict__ bn2q) {
  __shared__ float zr[H];
  int blk = blockIdx.x;
  int b = blk >> 8, n = blk & 255;
  int tid = threadIdx.x;
  float mean = bn1s[n] * (1.0f / 1024.0f);
  float var = bn1q[n] * (1.0f / 1024.0f) - mean * mean;
  float inv = rsqrtf(var + 1e-5f);
  float a = g1[n] * inv;
  float c0 = be1[n] - a * mean;
  zr[tid] = a * H1[((size_t)(b * N + n)) * H + tid] + c0;
  __syncthreads();
  float acc = b2[tid];
  for (int c = 0; c < H; c += 4) {
    const float4 z = *(const float4*)&zr[c];
    acc = fmaf(z.x, W2[(c + 0) * H + tid], acc);
    acc = fmaf(z.y, W2[(c + 1) * H + tid], acc);
    acc = fmaf(z.z, W2[(c + 2) * H + tid], acc);
    acc = fmaf(z.w, W2[(c + 3) * H + tid], acc);
  }
  float v = fmaxf(acc, 0.0f);
  H2[((size_t)(b * N + n)) * H + tid] = v;
  float s = v, q = v * v;
  for (int off = 32; off; off >>= 1) {
    s += __shfl_down(s, off);
    q += __shfl_down(q, off);
  }
  if ((tid & 63) == 0) {
    atomicAdd(&bn2s[n], s);
    atomicAdd(&bn2q[n], q);
  }
}

// ---------------------------------------------------------------- K6: out = BN2(H2)
__global__ __launch_bounds__(256) void k_bn2out(
    const float* __restrict__ H2, const float* __restrict__ g2,
    const float* __restrict__ be2, const float* __restrict__ bn2s,
    const float* __restrict__ bn2q, float* __restrict__ out) {
  int idx = blockIdx.x * 256 + threadIdx.x;
  int n = (idx >> 8) & 255;
  float mean = bn2s[n] * (1.0f / 1024.0f);
  float var = bn2q[n] * (1.0f / 1024.0f) - mean * mean;
  float inv = rsqrtf(var + 1e-5f);
  out[idx] = g2[n] * (H2[idx] - mean) * inv + be2[n];
}

// ----------------------------------------------------------------
extern "C" void kernel_launch(void* const* d_in, const int* in_sizes, int n_in,
                              void* d_out, int out_size, void* d_ws, size_t ws_size,
                              hipStream_t stream) {
  const float* A   = (const float*)d_in[0];
  const float* X   = (const float*)d_in[1];
  const float* eps = (const float*)d_in[2];
  const float* W1  = (const float*)d_in[3];
  const float* b1  = (const float*)d_in[4];
  const float* g1  = (const float*)d_in[5];
  const float* be1 = (const float*)d_in[6];
  const float* W2  = (const float*)d_in[7];
  const float* b2  = (const float*)d_in[8];
  const float* g2  = (const float*)d_in[9];
  const float* be2 = (const float*)d_in[10];
  const float* W3  = (const float*)d_in[11];
  const float* b3  = (const float*)d_in[12];
  const float* W4  = (const float*)d_in[13];
  const float* b4  = (const float*)d_in[14];
  float* out = (float*)d_out;

  char* ws = (char*)d_ws;
  uint64_t* adjMask = (uint64_t*)ws; ws += (size_t)B * N * 4 * 8;   // 32 KB
  unsigned* edgeCnt = (unsigned*)ws; ws += 256;
  unsigned* edges   = (unsigned*)ws; ws += (size_t)B * MAXE * 4;    // 128 KB
  unsigned* deg     = (unsigned*)ws; ws += (size_t)B * N * 4;       // 4 KB
  uint8_t*  nbr     = (uint8_t*)ws;  ws += (size_t)B * N * 64;      // 64 KB
  ushort*   W3T     = (ushort*)ws;   ws += (size_t)D * H * 2;       // 64 KB
  ushort*   W4T     = (ushort*)ws;   ws += (size_t)H * D * 2;       // 64 KB
  float* Xn   = (float*)ws;          ws += (size_t)B * N * D * 4;   // 512 KB
  float* H1   = (float*)ws;          ws += (size_t)B * N * H * 4;   // 1 MB
  float* H2   = (float*)ws;          ws += (size_t)B * N * H * 4;   // 1 MB
  float* bn1s = (float*)ws;          ws += N * 4;
  float* bn1q = (float*)ws;          ws += N * 4;
  float* bn2s = (float*)ws;          ws += N * 4;
  float* bn2q = (float*)ws;          ws += N * 4;

  hipMemsetAsync(edgeCnt, 0, 256, stream);
  hipMemsetAsync(bn1s, 0, 4 * N * sizeof(float), stream);

  k_prep<<<(2 * D * H) / 256, 256, 0, stream>>>(W3, W4, W3T, W4T);
  k_adj_edges<<<B * N, 64, 0, stream>>>(A, adjMask, deg, nbr, edgeCnt, edges);
  k_xstd<<<B * N, D, 0, stream>>>(X, eps, deg, nbr, Xn);
  k_mlp2<<<B * NT, 256, 0, stream>>>(X, edges, edgeCnt, adjMask, W3T, b3, W4T, b4, Xn);
  k_mlp1a<<<B * N, H, 0, stream>>>(Xn, W1, b1, H1, bn1s, bn1q);
  k_mlp1b<<<B * N, H, 0, stream>>>(H1, W2, b2, g1, be1, bn1s, bn1q, H2, bn2s, bn2q);
  k_bn2out<<<(B * N * H) / 256, 256, 0, stream>>>(H2, g2, be2, bn2s, bn2q, out);
}